// Round 14
// baseline (28.470 us; speedup 1.0000x reference)
//
#include <hip/hip_runtime.h>
#include <math.h>

// DifferentiableLogicLayer:
//   out[b,g] = c0[g] + ca[g]*a + cb[g]*b + cab[g]*a*b   (affine collapse of
//   the 16 soft-logic ops dotted with softmax(gate_logits[g]))
//   a = clip(x[b, g%8192]), b = clip(x[b, (g+1)%8192])
//
// R13 lesson: lane-63-masked neighbor load neutral => all-lane L1/L2-hit
// scalar re-read is free here. R14: exploit that — DROP the __shfl_down
// entirely; the prefetched all-lane scalar xr[gn] IS x[row, g+4], the b
// operand of gate g+3, for every lane. Removes ds_permute + lgkmcnt wait
// from every iteration's dependency chain. Single change vs R12.

constexpr int INPUT_SIZE = 8192;
constexpr int BATCH      = 2048;
constexpr int NBLOCKS    = 2048;             // 32 colblocks x 64 rowblocks
constexpr int NITER      = 8;                // rows per thread (stride 256)

typedef float floatx4 __attribute__((ext_vector_type(4)));

__device__ __forceinline__ floatx4 softmax_affine(const float* __restrict__ logits, int g) {
    const floatx4* lp = reinterpret_cast<const floatx4*>(logits + (size_t)g * 16);
    floatx4 l0 = lp[0], l1 = lp[1], l2 = lp[2], l3 = lp[3];
    float p[16];
    p[0]=l0.x;  p[1]=l0.y;  p[2]=l0.z;  p[3]=l0.w;
    p[4]=l1.x;  p[5]=l1.y;  p[6]=l1.z;  p[7]=l1.w;
    p[8]=l2.x;  p[9]=l2.y;  p[10]=l2.z; p[11]=l2.w;
    p[12]=l3.x; p[13]=l3.y; p[14]=l3.z; p[15]=l3.w;

    float m = p[0];
    #pragma unroll
    for (int i = 1; i < 16; ++i) m = fmaxf(m, p[i]);
    float s = 0.f;
    #pragma unroll
    for (int i = 0; i < 16; ++i) { p[i] = __expf(p[i] - m); s += p[i]; }
    float inv = 1.f / s;

    float c0  = p[8]+p[9]+p[10]+p[11]+p[12]+p[13]+p[14]+p[15];
    float ca  = p[2]+p[3]+p[6]+p[7] - p[8]-p[9]-p[12]-p[13];
    float cb  = p[4]+p[5]+p[6]+p[7] - p[8]-p[9]-p[10]-p[11];
    float cab = p[1]-p[2]-p[4]-2.f*p[6]-p[7]+p[8]+2.f*p[9]+p[11]+p[13]-p[14];
    floatx4 wv = { c0*inv, ca*inv, cb*inv, cab*inv };
    return wv;
}

__global__ __launch_bounds__(256) void dll_fused_colmajor(
    const float* __restrict__ x,
    const float* __restrict__ logits,
    float* __restrict__ out) {

    __shared__ floatx4 wlds[256];            // this block's 256 gate weights

    int colblock = blockIdx.x & 31;          // 32 column blocks
    int rowblock = blockIdx.x >> 5;          // 64 row blocks
    int c_local  = threadIdx.x & 63;         // lane == column within wave
    int rslot    = threadIdx.x >> 6;         // 4 row-slots per block

    int col4 = colblock * 64 + c_local;      // fixed col4 slot (wave: unit-stride)
    int g    = col4 * 4;
    int gn   = (g + 4) & (INPUT_SIZE - 1);   // wrap neighbor index
    int row0 = rowblock * 4 + rslot;         // 0 .. 255

    // ---- prefetch row-0's loads BEFORE the prologue (hides softmax) ------
    const float* xr0 = x + (size_t)row0 * INPUT_SIZE;
    floatx4 xv_c   = *reinterpret_cast<const floatx4*>(xr0 + g);
    float   nb_raw = xr0[gn];                // all lanes: = x[row, g+4]

    // ---- prologue: ONE softmax per thread, shared via LDS ----------------
    wlds[threadIdx.x] = softmax_affine(logits, colblock * 256 + threadIdx.x);
    __syncthreads();

    floatx4 w0 = wlds[c_local * 4 + 0];
    floatx4 w1 = wlds[c_local * 4 + 1];
    floatx4 w2 = wlds[c_local * 4 + 2];
    floatx4 w3 = wlds[c_local * 4 + 3];

    // ---- stream loop (no shuffle: neighbor comes from its own load) ------
    #pragma unroll
    for (int it = 0; it < NITER; ++it) {
        int row = row0 + it * 256;

        float a0 = fminf(fmaxf(xv_c.x,  0.f), 1.f);
        float a1 = fminf(fmaxf(xv_c.y,  0.f), 1.f);
        float a2 = fminf(fmaxf(xv_c.z,  0.f), 1.f);
        float a3 = fminf(fmaxf(xv_c.w,  0.f), 1.f);
        float a4 = fminf(fmaxf(nb_raw,  0.f), 1.f);

        floatx4 o;
        o.x = fmaf(w0.w, a0 * a1, fmaf(w0.z, a1, fmaf(w0.y, a0, w0.x)));
        o.y = fmaf(w1.w, a1 * a2, fmaf(w1.z, a2, fmaf(w1.y, a1, w1.x)));
        o.z = fmaf(w2.w, a2 * a3, fmaf(w2.z, a3, fmaf(w2.y, a2, w2.x)));
        o.w = fmaf(w3.w, a3 * a4, fmaf(w3.z, a4, fmaf(w3.y, a3, w3.x)));

        // prefetch next iteration before the store (compiler pipelines)
        if (it + 1 < NITER) {
            const float* xr = x + (size_t)(row + 256) * INPUT_SIZE;
            xv_c   = *reinterpret_cast<const floatx4*>(xr + g);
            nb_raw = xr[gn];
        }

        *reinterpret_cast<floatx4*>(out + (size_t)row * INPUT_SIZE + g) = o;
    }
}

extern "C" void kernel_launch(void* const* d_in, const int* in_sizes, int n_in,
                              void* d_out, int out_size, void* d_ws, size_t ws_size,
                              hipStream_t stream) {
    const float* x      = reinterpret_cast<const float*>(d_in[0]);
    const float* logits = reinterpret_cast<const float*>(d_in[1]);
    float*       out    = reinterpret_cast<float*>(d_out);

    dll_fused_colmajor<<<NBLOCKS, 256, 0, stream>>>(x, logits, out);
}

// Round 15
// 26.971 us; speedup vs baseline: 1.0556x; 1.0556x over previous
//
#include <hip/hip_runtime.h>
#include <math.h>

// DifferentiableLogicLayer:
//   out[b,g] = c0[g] + ca[g]*a + cb[g]*b + cab[g]*a*b   (affine collapse of
//   the 16 soft-logic ops dotted with softmax(gate_logits[g]))
//   a = clip(x[b, g%8192]), b = clip(x[b, (g+1)%8192])
//
// R12/R13/R14 A/B/C settled neighbor handling: shfl for lanes 0-62 +
// lane-63 consumes prefetched scalar (R12) is optimal. R15: last knob —
// grid geometry. 4096 blocks x 4 rows/thread (vs 2048 x 8): halves the
// per-thread tail, better XCD balance; softmax redundancy doubles but is
// LDS-shared (~+0.5us chip-wide). Inner loop byte-identical to R12.
// Pre-commit: flat => ~27us is this op's practical floor (75% of the
// 6.29 TB/s copy ceiling), declare roofline.

constexpr int INPUT_SIZE = 8192;
constexpr int BATCH      = 2048;
constexpr int NBLOCKS    = 4096;             // 32 colblocks x 128 rowblocks
constexpr int NITER      = 4;                // rows per thread (stride 512)
constexpr int ROW_SPAN   = 512;              // 128 rowblocks x 4 rslots

typedef float floatx4 __attribute__((ext_vector_type(4)));

__device__ __forceinline__ floatx4 softmax_affine(const float* __restrict__ logits, int g) {
    const floatx4* lp = reinterpret_cast<const floatx4*>(logits + (size_t)g * 16);
    floatx4 l0 = lp[0], l1 = lp[1], l2 = lp[2], l3 = lp[3];
    float p[16];
    p[0]=l0.x;  p[1]=l0.y;  p[2]=l0.z;  p[3]=l0.w;
    p[4]=l1.x;  p[5]=l1.y;  p[6]=l1.z;  p[7]=l1.w;
    p[8]=l2.x;  p[9]=l2.y;  p[10]=l2.z; p[11]=l2.w;
    p[12]=l3.x; p[13]=l3.y; p[14]=l3.z; p[15]=l3.w;

    float m = p[0];
    #pragma unroll
    for (int i = 1; i < 16; ++i) m = fmaxf(m, p[i]);
    float s = 0.f;
    #pragma unroll
    for (int i = 0; i < 16; ++i) { p[i] = __expf(p[i] - m); s += p[i]; }
    float inv = 1.f / s;

    float c0  = p[8]+p[9]+p[10]+p[11]+p[12]+p[13]+p[14]+p[15];
    float ca  = p[2]+p[3]+p[6]+p[7] - p[8]-p[9]-p[12]-p[13];
    float cb  = p[4]+p[5]+p[6]+p[7] - p[8]-p[9]-p[10]-p[11];
    float cab = p[1]-p[2]-p[4]-2.f*p[6]-p[7]+p[8]+2.f*p[9]+p[11]+p[13]-p[14];
    floatx4 wv = { c0*inv, ca*inv, cb*inv, cab*inv };
    return wv;
}

__global__ __launch_bounds__(256) void dll_fused_colmajor(
    const float* __restrict__ x,
    const float* __restrict__ logits,
    float* __restrict__ out) {

    __shared__ floatx4 wlds[256];            // this block's 256 gate weights

    int colblock = blockIdx.x & 31;          // 32 column blocks
    int rowblock = blockIdx.x >> 5;          // 128 row blocks
    int c_local  = threadIdx.x & 63;         // lane == column within wave
    int rslot    = threadIdx.x >> 6;         // 4 row-slots per block

    int col4 = colblock * 64 + c_local;      // fixed col4 slot (wave: unit-stride)
    int g    = col4 * 4;
    int gn   = (g + 4) & (INPUT_SIZE - 1);   // wrap neighbor index
    int row0 = rowblock * 4 + rslot;         // 0 .. 511

    // ---- prefetch row-0's loads BEFORE the prologue (hides softmax) ------
    const float* xr0 = x + (size_t)row0 * INPUT_SIZE;
    floatx4 xv_c   = *reinterpret_cast<const floatx4*>(xr0 + g);
    float   nb_raw = xr0[gn];                // all lanes; lane 63 consumes

    // ---- prologue: ONE softmax per thread, shared via LDS ----------------
    wlds[threadIdx.x] = softmax_affine(logits, colblock * 256 + threadIdx.x);
    __syncthreads();

    floatx4 w0 = wlds[c_local * 4 + 0];
    floatx4 w1 = wlds[c_local * 4 + 1];
    floatx4 w2 = wlds[c_local * 4 + 2];
    floatx4 w3 = wlds[c_local * 4 + 3];

    // ---- stream loop (R12 inner loop, byte-identical) ---------------------
    #pragma unroll
    for (int it = 0; it < NITER; ++it) {
        int row = row0 + it * ROW_SPAN;

        float nb = __shfl_down(xv_c.x, 1);
        if (c_local == 63) nb = nb_raw;

        float a0 = fminf(fmaxf(xv_c.x, 0.f), 1.f);
        float a1 = fminf(fmaxf(xv_c.y, 0.f), 1.f);
        float a2 = fminf(fmaxf(xv_c.z, 0.f), 1.f);
        float a3 = fminf(fmaxf(xv_c.w, 0.f), 1.f);
        float a4 = fminf(fmaxf(nb,     0.f), 1.f);

        floatx4 o;
        o.x = fmaf(w0.w, a0 * a1, fmaf(w0.z, a1, fmaf(w0.y, a0, w0.x)));
        o.y = fmaf(w1.w, a1 * a2, fmaf(w1.z, a2, fmaf(w1.y, a1, w1.x)));
        o.z = fmaf(w2.w, a2 * a3, fmaf(w2.z, a3, fmaf(w2.y, a2, w2.x)));
        o.w = fmaf(w3.w, a3 * a4, fmaf(w3.z, a4, fmaf(w3.y, a3, w3.x)));

        // prefetch next iteration before the store (compiler pipelines)
        if (it + 1 < NITER) {
            const float* xr = x + (size_t)(row + ROW_SPAN) * INPUT_SIZE;
            xv_c   = *reinterpret_cast<const floatx4*>(xr + g);
            nb_raw = xr[gn];
        }

        *reinterpret_cast<floatx4*>(out + (size_t)row * INPUT_SIZE + g) = o;
    }
}

extern "C" void kernel_launch(void* const* d_in, const int* in_sizes, int n_in,
                              void* d_out, int out_size, void* d_ws, size_t ws_size,
                              hipStream_t stream) {
    const float* x      = reinterpret_cast<const float*>(d_in[0]);
    const float* logits = reinterpret_cast<const float*>(d_in[1]);
    float*       out    = reinterpret_cast<float*>(d_out);

    dll_fused_colmajor<<<NBLOCKS, 256, 0, stream>>>(x, logits, out);
}